// Round 5
// baseline (63.288 us; speedup 1.0000x reference)
//
#include <hip/hip_runtime.h>
#include <math.h>

// SSIM char-matcher: img (1,1,1024,768) f32, chars (95,1,16,6) f32 -> argmax idx [64][128] int32
// H=16, W=6, WIN=3, tiles T=8192 (64 rows x 128 cols), refs R=95 (pad to 96)
// Grid: 512 blocks = (64 rows) x (4 col-groups of 32 tiles) x (2 ref-halves of 48)

static constexpr float kC1 = 1.0e-4f;   // 0.01^2
static constexpr float kC2 = 9.0e-4f;   // 0.03^2

struct KF { float k[9]; };

__device__ __forceinline__ int refl(int x, int n) {
  if (x < 0) return -x;
  if (x >= n) return 2 * n - 2 - x;
  return x;
}

// ---------------- Kernel 1: per-ref precompute ----------------
// refdata: per (hw, half) a chunk of 48 rows x 12 floats (2304 B, contiguous).
// Logical ref rloc (0..47) stored at physical row rp = rloc/6 + 8*(rloc%6)
// (bank-spreading permutation: a wave's 8 rthr-lanes read 8 consecutive rows).
// Row contents: f0..8 = 2*k[k]*Rp[k] (DOUBLED), f9 = 2*mu_r (DOUBLED),
// f10 = mu_r^2 + C1, f11 = sig_r + C2.  r=95 is padding (never argmax'd).
__global__ __launch_bounds__(128) void refprep_kernel(
    const float* __restrict__ chars, float* __restrict__ refdata,
    float* __restrict__ densR, KF kf) {
  const int hw = blockIdx.x;   // 0..95
  const int r = threadIdx.x;   // 0..127
  if (r >= 96) return;
  const int half = r / 48;
  const int rloc = r - half * 48;
  const int rp = rloc / 6 + 8 * (rloc % 6);
  float* row = refdata + ((size_t)(hw * 2 + half) * 48 + rp) * 12;
  const int h = hw / 6, w = hw % 6;
  if (r < 95) {
    const float* cb = chars + r * 96;
    float mu = 0.f, ex2 = 0.f;
    float wrv[9];
#pragma unroll
    for (int i = 0; i < 3; ++i) {
      const int hh = refl(h + i - 1, 16);
#pragma unroll
      for (int j = 0; j < 3; ++j) {
        const int ww = refl(w + j - 1, 6);
        const float p = cb[hh * 6 + ww];
        const float kv = kf.k[i * 3 + j];
        wrv[i * 3 + j] = 2.0f * kv * p;
        mu += kv * p;
        ex2 += kv * p * p;
      }
    }
    const float sig = ex2 - mu * mu;
#pragma unroll
    for (int k = 0; k < 9; ++k) row[k] = wrv[k];
    row[9]  = 2.0f * mu;
    row[10] = mu * mu + kC1;
    row[11] = sig + kC2;
  } else {
#pragma unroll
    for (int k = 0; k < 9; ++k) row[k] = 0.f;
    row[9]  = 0.f;
    row[10] = kC1;
    row[11] = kC2;
  }
  if (hw == 0) {
    if (r < 95) {
      float s = 0.f;
      for (int i = 0; i < 96; ++i) s += chars[r * 96 + i];
      densR[r] = s * (1.0f / 96.0f);
    } else {
      densR[r] = 0.f;
    }
  }
}

// ---- async global->LDS staging of one 576-float (2304 B) ref chunk ----
// 2 x (64 lanes x 16B) + 1 x (64 lanes x 4B); counts 3 on vmcnt.
__device__ __forceinline__ void stage_px(const float* __restrict__ src,
                                         float* dst, int lane) {
  const uintptr_t gs = (uintptr_t)src;
  const uintptr_t ls = (uintptr_t)dst;
#define G_(off) ((const __attribute__((address_space(1))) void*)(gs + (off)))
#define L_(off) ((__attribute__((address_space(3))) void*)(uint32_t)(ls + (off)))
  __builtin_amdgcn_global_load_lds(G_(0    + lane * 16), L_(0),    16, 0, 0);
  __builtin_amdgcn_global_load_lds(G_(1024 + lane * 16), L_(1024), 16, 0, 0);
  __builtin_amdgcn_global_load_lds(G_(2048 + lane * 4),  L_(2048), 4, 0, 0);
#undef G_
#undef L_
}

// ---------------- Kernel 2: main SSIM ----------------
// 512 blocks x 512 threads (8 waves). Block = 32 tiles x 48 refs x 96 px.
// Wave w owns px [12w, 12w+12) = 2 full pixel-rows. lane = tthr(8 x 4 tiles)
// x rthr(8 x 6 refs) -> 24 el/thread. Wave-private double-buffered ref chunk,
// zero main-loop barriers, counted vmcnt(3). Score via rcp + 1 Newton step.
//
// Occupancy pinning: LDS (80 KB) caps at 2 blocks/CU = 4 waves/EU. HIP's
// __launch_bounds__(512) emits flat-work-group-size(1,512); the min=1 lets
// the VGPR allocator believe an 8-waves/EU tier exists -> it squeezed to
// 64 VGPR and spilled ~20 regs (R3/R4: WRITE_SIZE 15-24 MB of scratch).
// Exact flat_work_group_size(512,512) + waves_per_eu(4,4) kills that tier:
// full 128-VGPR budget, no spills.
__global__ __attribute__((amdgpu_flat_work_group_size(512, 512),
                          amdgpu_waves_per_eu(4, 4)))
void ssim_main_kernel(
    const float* __restrict__ img, const float* __restrict__ refdata,
    const float* __restrict__ densR, float2* __restrict__ scratch, KF kf) {
  // [0:4608) padT [144][32] | [4608:10752) statT [2][96][32] |
  // [10752:19968) refbuf 8 waves x 2 x 576.  Overlay after loop: sb[8][32][49].
  __shared__ float smem[19968];
  __shared__ float densT[32];
  float* padT = smem;
  float* statT = smem + 4608;

  const int tid = threadIdx.x;
  const int w = tid >> 6;
  const int lane = tid & 63;
  const int tthr = lane >> 3;      // 0..7 -> 4 tiles
  const int rthr = lane & 7;       // 0..7 -> 6 refs
  const int tl0 = tthr * 4;
  const int blk = blockIdx.x;
  const int row0 = blk >> 3;           // tile-row 0..63
  const int colg = (blk >> 1) & 3;
  const int half = blk & 1;
  const int c0 = colg * 32;
  const int hwBase = w * 12;           // multiple of 6: wave = 2 full px-rows
  float* rbuf = smem + 10752 + w * 1152;   // wave-private 2 x 576

  // Issue px0 staging immediately (latency hides under phases A/B).
  stage_px(refdata + (size_t)(hwBase * 2 + half) * 576, rbuf, lane);

  // Phase A: reflect-padded tiles, transposed: padT[c(0..143)][tile(0..31)]
  for (int idx = tid; idx < 4608; idx += 512) {
    const int c = idx >> 5, tl = idx & 31;
    const int ph = c >> 3, pw = c & 7;
    const int h = refl(ph - 1, 16), ww = refl(pw - 1, 6);
    padT[idx] = img[(row0 * 16 + h) * 768 + (c0 + tl) * 6 + ww];
  }
  __syncthreads();

  if (tid < 32) {
    float s = 0.f;
    for (int h = 0; h < 16; ++h)
      for (int ww = 0; ww < 6; ++ww)
        s += padT[((h + 1) * 8 + (ww + 1)) * 32 + tid];
    densT[tid] = s * (1.0f / 96.0f);
  }
  // Phase B: per-(hw, tile) stats: mu, sig
  for (int idx = tid; idx < 3072; idx += 512) {
    const int hw = idx >> 5, tl = idx & 31;
    const int h = hw / 6, ww = hw % 6;
    float mu = 0.f, ex2 = 0.f;
#pragma unroll
    for (int i = 0; i < 3; ++i)
#pragma unroll
      for (int j = 0; j < 3; ++j) {
        const float p = padT[((h + i) * 8 + (ww + j)) * 32 + tl];
        const float kv = kf.k[i * 3 + j];
        mu += kv * p;
        ex2 += kv * p * p;
      }
    statT[idx] = mu;
    statT[3072 + idx] = ex2 - mu * mu;
  }
  __syncthreads();

  float score[4][6];
#pragma unroll
  for (int i = 0; i < 4; ++i)
#pragma unroll
    for (int j = 0; j < 6; ++j) score[i][j] = 0.f;

  // Incremental addressing (hwBase % 6 == 0): w6 cycles 0..5 twice.
  int pb = (2 * w) * 8 * 32 + tl0;     // padT offset of window origin
  int sbase = hwBase * 32 + tl0;       // statT offset
  const float* refsrc = refdata + (size_t)((hwBase + 1) * 2 + half) * 576;
  int w6 = 0;

#pragma unroll 1
  for (int it = 0; it < 12; ++it) {
    const float* buf = rbuf + (it & 1) * 576;

    if (it < 11) {
      // Restaged buffer's last reads were consumed (hence retired) in it-1:
      // no lgkm fence needed. Counted vmcnt: next stage stays in flight.
      stage_px(refsrc, rbuf + ((it + 1) & 1) * 576, lane);
      asm volatile("s_waitcnt vmcnt(3)" ::: "memory");
    } else {
      asm volatile("s_waitcnt vmcnt(0)" ::: "memory");
    }
    refsrc += 1152;

    // e[i][j] = C2 + sum_k Tp[k][tile_i] * (2*k[k]*Rp[k][ref_j])
    float e[4][6];
#pragma unroll
    for (int i = 0; i < 4; ++i)
#pragma unroll
      for (int j = 0; j < 6; ++j) e[i][j] = kC2;

    // ---- k = 0..3 ----
    {
      float tpA[4][4];
      {
        const int off[4] = {0, 32, 64, 256};   // (ik*8+jk)*32 for k=0..3
#pragma unroll
        for (int k = 0; k < 4; ++k) {
          const float4 t = *(const float4*)&padT[pb + off[k]];
          tpA[k][0] = t.x; tpA[k][1] = t.y; tpA[k][2] = t.z; tpA[k][3] = t.w;
        }
      }
#pragma unroll
      for (int j = 0; j < 6; ++j) {
        const float4 wa = *(const float4*)&buf[(rthr + 8 * j) * 12];
#pragma unroll
        for (int i = 0; i < 4; ++i) {
          e[i][j] = fmaf(tpA[0][i], wa.x, e[i][j]);
          e[i][j] = fmaf(tpA[1][i], wa.y, e[i][j]);
          e[i][j] = fmaf(tpA[2][i], wa.z, e[i][j]);
          e[i][j] = fmaf(tpA[3][i], wa.w, e[i][j]);
        }
      }
    }

    // tile stats
    float mu[4], sg[4], mt2[4];
    {
      const float4 m = *(const float4*)&statT[sbase];
      const float4 s = *(const float4*)&statT[3072 + sbase];
      mu[0]=m.x; mu[1]=m.y; mu[2]=m.z; mu[3]=m.w;
      sg[0]=s.x; sg[1]=s.y; sg[2]=s.z; sg[3]=s.w;
#pragma unroll
      for (int i = 0; i < 4; ++i) mt2[i] = mu[i] * mu[i];
    }

    // ---- k = 4..8 + epilogue ----
    {
      float tpB[5][4];
      {
        const int off[5] = {288, 320, 512, 544, 576};  // k=4..8
#pragma unroll
        for (int k = 0; k < 5; ++k) {
          const float4 t = *(const float4*)&padT[pb + off[k]];
          tpB[k][0] = t.x; tpB[k][1] = t.y; tpB[k][2] = t.z; tpB[k][3] = t.w;
        }
      }
#pragma unroll
      for (int j = 0; j < 6; ++j) {
        const float4 wb = *(const float4*)&buf[(rthr + 8 * j) * 12 + 4];
        const float4 wc = *(const float4*)&buf[(rthr + 8 * j) * 12 + 8];
#pragma unroll
        for (int i = 0; i < 4; ++i) {
          float ev = e[i][j];
          ev = fmaf(tpB[0][i], wb.x, ev);
          ev = fmaf(tpB[1][i], wb.y, ev);
          ev = fmaf(tpB[2][i], wb.z, ev);
          ev = fmaf(tpB[3][i], wb.w, ev);
          ev = fmaf(tpB[4][i], wc.x, ev);
          // wc.y = 2*mu_r, wc.z = mu_r^2+C1, wc.w = sig_r+C2
          const float am = mu[i] * wc.y;             // 2*mt*mr
          const float n1 = am + kC1;
          const float n2 = ev - am;                  // 2*sig_tr + C2
          const float d1 = mt2[i] + wc.z;            // mt^2+mr^2+C1
          const float d2 = sg[i] + wc.w;
          const float nn = n1 * n2;
          const float dd = d1 * d2;
          // rcp + 1 Newton step: ~1e-7 rel error, no IEEE div, 1 accum reg.
          const float r0v = __builtin_amdgcn_rcpf(dd);
          const float r1v = r0v * fmaf(-dd, r0v, 2.0f);
          score[i][j] = fmaf(nn, r1v, score[i][j]);
        }
      }
    }

    pb += (w6 == 5) ? 96 : 32;       // col step 32; row wrap: +3 window cols
    w6 = (w6 == 5) ? 0 : w6 + 1;
    sbase += 32;
  }

  // sb overlay: all waves must be done with padT/statT/refbuf
  __syncthreads();
  float* sb = smem;   // [8][32][49]
#pragma unroll
  for (int i = 0; i < 4; ++i)
#pragma unroll
    for (int j = 0; j < 6; ++j)
      sb[w * 1568 + (tl0 + i) * 49 + (rthr * 6 + j)] = score[i][j];
  __syncthreads();

  // Reduce 8 wave-partials + density penalty + per-tile argmax
  {
    const int tile = tid >> 4, rt = tid & 15;
    const float dt = densT[tile];
    float best = -1e30f; int bi = 0;
#pragma unroll
    for (int q = 0; q < 3; ++q) {
      const int rr = rt * 3 + q;
      const int rg = half * 48 + rr;
      if (rg < 95) {
        float s = 0.f;
#pragma unroll
        for (int g = 0; g < 8; ++g) s += sb[g * 1568 + tile * 49 + rr];
        s = s * (1.0f / 96.0f) - 3.0f * fabsf(dt - densR[rg]);
        if (s > best) { best = s; bi = rg; }   // ascending r, strict >
      }
    }
#pragma unroll
    for (int m = 8; m >= 1; m >>= 1) {
      const float ob = __shfl_xor(best, m, 64);
      const int oi = __shfl_xor(bi, m, 64);
      if (ob > best || (ob == best && oi < bi)) { best = ob; bi = oi; }
    }
    if (rt == 0)
      scratch[half * 8192 + row0 * 128 + c0 + tile] = make_float2(best, (float)bi);
  }
}

// ---------------- Kernel 3: combine ref-halves ----------------
__global__ __launch_bounds__(256) void combine_kernel(
    const float2* __restrict__ scratch, int* __restrict__ out) {
  const int t = blockIdx.x * 256 + threadIdx.x;   // 0..8191
  const float2 a = scratch[t];
  const float2 b = scratch[8192 + t];
  out[t] = (b.x > a.x) ? (int)b.y : (int)a.y;     // ties -> half0 (lower r)
}

// ---------------- Host launch ----------------
extern "C" void kernel_launch(void* const* d_in, const int* in_sizes, int n_in,
                              void* d_out, int out_size, void* d_ws, size_t ws_size,
                              hipStream_t stream) {
  (void)in_sizes; (void)n_in; (void)out_size; (void)ws_size;
  const float* img = (const float*)d_in[0];
  const float* chars = (const float*)d_in[1];
  int* out = (int*)d_out;
  float* refdata = (float*)d_ws;                  // 96*2*48*12 = 110592 floats
  float* densR = refdata + 110592;                // +96
  float2* scratch = (float2*)(refdata + 110688);  // 2*8192 float2

  KF kf;
  {
    float gg[3], s = 0.f;
    for (int i = 0; i < 3; ++i) {
      const float c = (float)i - 1.0f;
      gg[i] = expf(-(c * c) / (2.0f * 1.5f * 1.5f));
      s += gg[i];
    }
    float gn[3];
    for (int i = 0; i < 3; ++i) gn[i] = gg[i] / s;
    float k2[9]; float ks = 0.f;
    for (int i = 0; i < 3; ++i)
      for (int j = 0; j < 3; ++j) { k2[i * 3 + j] = gn[i] * gn[j]; ks += k2[i * 3 + j]; }
    for (int k = 0; k < 9; ++k) kf.k[k] = k2[k] / ks;
  }

  hipLaunchKernelGGL(refprep_kernel, dim3(96), dim3(128), 0, stream,
                     chars, refdata, densR, kf);
  hipLaunchKernelGGL(ssim_main_kernel, dim3(512), dim3(512), 0, stream,
                     img, refdata, densR, scratch, kf);
  hipLaunchKernelGGL(combine_kernel, dim3(32), dim3(256), 0, stream,
                     scratch, out);
}

// Round 6
// 63.252 us; speedup vs baseline: 1.0006x; 1.0006x over previous
//
#include <hip/hip_runtime.h>
#include <math.h>

// SSIM char-matcher: img (1,1,1024,768) f32, chars (95,1,16,6) f32 -> argmax idx [64][128] int32
// H=16, W=6, WIN=3, tiles T=8192 (64 rows x 128 cols), refs R=95 (pad to 96)
// Grid: 512 blocks = (64 rows) x (4 col-groups of 32 tiles) x (2 ref-halves of 48)

static constexpr float kC1 = 1.0e-4f;   // 0.01^2
static constexpr float kC2 = 9.0e-4f;   // 0.03^2

struct KF { float k[9]; };

__device__ __forceinline__ int refl(int x, int n) {
  if (x < 0) return -x;
  if (x >= n) return 2 * n - 2 - x;
  return x;
}

// ---------------- Kernel 1: per-ref precompute ----------------
// refdata: per (hw, half) a chunk of 48 rows x 12 floats (2304 B, contiguous).
// Logical ref rloc (0..47) stored at physical row rp = rloc/6 + 8*(rloc%6)
// (bank-spreading permutation: a wave's 8 rthr-lanes read 8 consecutive rows).
// Row contents: f0..8 = 2*k[k]*Rp[k] (DOUBLED), f9 = 2*mu_r (DOUBLED),
// f10 = mu_r^2 + C1, f11 = sig_r + C2.  r=95 is padding (never argmax'd).
__global__ __launch_bounds__(128) void refprep_kernel(
    const float* __restrict__ chars, float* __restrict__ refdata,
    float* __restrict__ densR, KF kf) {
  const int hw = blockIdx.x;   // 0..95
  const int r = threadIdx.x;   // 0..127
  if (r >= 96) return;
  const int half = r / 48;
  const int rloc = r - half * 48;
  const int rp = rloc / 6 + 8 * (rloc % 6);
  float* row = refdata + ((size_t)(hw * 2 + half) * 48 + rp) * 12;
  const int h = hw / 6, w = hw % 6;
  if (r < 95) {
    const float* cb = chars + r * 96;
    float mu = 0.f, ex2 = 0.f;
    float wrv[9];
#pragma unroll
    for (int i = 0; i < 3; ++i) {
      const int hh = refl(h + i - 1, 16);
#pragma unroll
      for (int j = 0; j < 3; ++j) {
        const int ww = refl(w + j - 1, 6);
        const float p = cb[hh * 6 + ww];
        const float kv = kf.k[i * 3 + j];
        wrv[i * 3 + j] = 2.0f * kv * p;
        mu += kv * p;
        ex2 += kv * p * p;
      }
    }
    const float sig = ex2 - mu * mu;
#pragma unroll
    for (int k = 0; k < 9; ++k) row[k] = wrv[k];
    row[9]  = 2.0f * mu;
    row[10] = mu * mu + kC1;
    row[11] = sig + kC2;
  } else {
#pragma unroll
    for (int k = 0; k < 9; ++k) row[k] = 0.f;
    row[9]  = 0.f;
    row[10] = kC1;
    row[11] = kC2;
  }
  if (hw == 0) {
    if (r < 95) {
      float s = 0.f;
      for (int i = 0; i < 96; ++i) s += chars[r * 96 + i];
      densR[r] = s * (1.0f / 96.0f);
    } else {
      densR[r] = 0.f;
    }
  }
}

// ---- async global->LDS staging of one 576-float (2304 B) ref chunk ----
// 2 x (64 lanes x 16B) + 1 x (64 lanes x 4B); counts 3 on vmcnt.
__device__ __forceinline__ void stage_px(const float* __restrict__ src,
                                         float* dst, int lane) {
  const uintptr_t gs = (uintptr_t)src;
  const uintptr_t ls = (uintptr_t)dst;
#define G_(off) ((const __attribute__((address_space(1))) void*)(gs + (off)))
#define L_(off) ((__attribute__((address_space(3))) void*)(uint32_t)(ls + (off)))
  __builtin_amdgcn_global_load_lds(G_(0    + lane * 16), L_(0),    16, 0, 0);
  __builtin_amdgcn_global_load_lds(G_(1024 + lane * 16), L_(1024), 16, 0, 0);
  __builtin_amdgcn_global_load_lds(G_(2048 + lane * 4),  L_(2048), 4, 0, 0);
#undef G_
#undef L_
}

// ---------------- Kernel 2: main SSIM ----------------
// 512 blocks x 512 threads (8 waves). Block = 32 tiles x 48 refs x 96 px.
// Wave w owns px [12w, 12w+12) = 2 full pixel-rows. lane = tthr(8 x 4 tiles)
// x rthr(8 x 6 refs) -> 24 el/thread. Wave-private double-buffered ref chunk,
// zero main-loop barriers, counted vmcnt(3). Score via rcp + 1 Newton step.
//
// VGPR-budget note (R2..R5 evidence): the ONLY spelling that yielded a
// 128-VGPR allocation on this toolchain is __launch_bounds__(512, 2)
// (R2: VGPR=128, no spills). Both (512,4) and
// flat_work_group_size(512,512)+waves_per_eu(4,4) resolved to the 64-VGPR
// tier and spilled ~24 regs (15-24 MB scratch writes, R3-R5). min=2 grants
// budget 256; actual pressure ~96 keeps allocation <=128, so the launch-time
// occupancy stays at the LDS-imposed 2 blocks/CU = 4 waves/EU.
__global__ __launch_bounds__(512, 2)
void ssim_main_kernel(
    const float* __restrict__ img, const float* __restrict__ refdata,
    const float* __restrict__ densR, float2* __restrict__ scratch, KF kf) {
  // [0:4608) padT [144][32] | [4608:10752) statT [2][96][32] |
  // [10752:19968) refbuf 8 waves x 2 x 576.  Overlay after loop: sb[8][32][49].
  __shared__ float smem[19968];
  __shared__ float densT[32];
  float* padT = smem;
  float* statT = smem + 4608;

  const int tid = threadIdx.x;
  const int w = tid >> 6;
  const int lane = tid & 63;
  const int tthr = lane >> 3;      // 0..7 -> 4 tiles
  const int rthr = lane & 7;       // 0..7 -> 6 refs
  const int tl0 = tthr * 4;
  const int blk = blockIdx.x;
  const int row0 = blk >> 3;           // tile-row 0..63
  const int colg = (blk >> 1) & 3;
  const int half = blk & 1;
  const int c0 = colg * 32;
  const int hwBase = w * 12;           // multiple of 6: wave = 2 full px-rows
  float* rbuf = smem + 10752 + w * 1152;   // wave-private 2 x 576

  // Issue px0 staging immediately (latency hides under phases A/B).
  stage_px(refdata + (size_t)(hwBase * 2 + half) * 576, rbuf, lane);

  // Phase A: reflect-padded tiles, transposed: padT[c(0..143)][tile(0..31)]
  for (int idx = tid; idx < 4608; idx += 512) {
    const int c = idx >> 5, tl = idx & 31;
    const int ph = c >> 3, pw = c & 7;
    const int h = refl(ph - 1, 16), ww = refl(pw - 1, 6);
    padT[idx] = img[(row0 * 16 + h) * 768 + (c0 + tl) * 6 + ww];
  }
  __syncthreads();

  if (tid < 32) {
    float s = 0.f;
    for (int h = 0; h < 16; ++h)
      for (int ww = 0; ww < 6; ++ww)
        s += padT[((h + 1) * 8 + (ww + 1)) * 32 + tid];
    densT[tid] = s * (1.0f / 96.0f);
  }
  // Phase B: per-(hw, tile) stats: mu, sig
  for (int idx = tid; idx < 3072; idx += 512) {
    const int hw = idx >> 5, tl = idx & 31;
    const int h = hw / 6, ww = hw % 6;
    float mu = 0.f, ex2 = 0.f;
#pragma unroll
    for (int i = 0; i < 3; ++i)
#pragma unroll
      for (int j = 0; j < 3; ++j) {
        const float p = padT[((h + i) * 8 + (ww + j)) * 32 + tl];
        const float kv = kf.k[i * 3 + j];
        mu += kv * p;
        ex2 += kv * p * p;
      }
    statT[idx] = mu;
    statT[3072 + idx] = ex2 - mu * mu;
  }
  __syncthreads();

  float score[4][6];
#pragma unroll
  for (int i = 0; i < 4; ++i)
#pragma unroll
    for (int j = 0; j < 6; ++j) score[i][j] = 0.f;

  // Incremental addressing (hwBase % 6 == 0): w6 cycles 0..5 twice.
  int pb = (2 * w) * 8 * 32 + tl0;     // padT offset of window origin
  int sbase = hwBase * 32 + tl0;       // statT offset
  const float* refsrc = refdata + (size_t)((hwBase + 1) * 2 + half) * 576;
  int w6 = 0;

#pragma unroll 1
  for (int it = 0; it < 12; ++it) {
    const float* buf = rbuf + (it & 1) * 576;

    if (it < 11) {
      // Restaged buffer's last reads were consumed (hence retired) in it-1:
      // no lgkm fence needed. Counted vmcnt: next stage stays in flight.
      stage_px(refsrc, rbuf + ((it + 1) & 1) * 576, lane);
      asm volatile("s_waitcnt vmcnt(3)" ::: "memory");
    } else {
      asm volatile("s_waitcnt vmcnt(0)" ::: "memory");
    }
    refsrc += 1152;

    // e[i][j] = C2 + sum_k Tp[k][tile_i] * (2*k[k]*Rp[k][ref_j])
    float e[4][6];
#pragma unroll
    for (int i = 0; i < 4; ++i)
#pragma unroll
      for (int j = 0; j < 6; ++j) e[i][j] = kC2;

    // ---- k = 0..3 ----
    {
      float tpA[4][4];
      {
        const int off[4] = {0, 32, 64, 256};   // (ik*8+jk)*32 for k=0..3
#pragma unroll
        for (int k = 0; k < 4; ++k) {
          const float4 t = *(const float4*)&padT[pb + off[k]];
          tpA[k][0] = t.x; tpA[k][1] = t.y; tpA[k][2] = t.z; tpA[k][3] = t.w;
        }
      }
#pragma unroll
      for (int j = 0; j < 6; ++j) {
        const float4 wa = *(const float4*)&buf[(rthr + 8 * j) * 12];
#pragma unroll
        for (int i = 0; i < 4; ++i) {
          e[i][j] = fmaf(tpA[0][i], wa.x, e[i][j]);
          e[i][j] = fmaf(tpA[1][i], wa.y, e[i][j]);
          e[i][j] = fmaf(tpA[2][i], wa.z, e[i][j]);
          e[i][j] = fmaf(tpA[3][i], wa.w, e[i][j]);
        }
      }
    }

    // tile stats
    float mu[4], sg[4], mt2[4];
    {
      const float4 m = *(const float4*)&statT[sbase];
      const float4 s = *(const float4*)&statT[3072 + sbase];
      mu[0]=m.x; mu[1]=m.y; mu[2]=m.z; mu[3]=m.w;
      sg[0]=s.x; sg[1]=s.y; sg[2]=s.z; sg[3]=s.w;
#pragma unroll
      for (int i = 0; i < 4; ++i) mt2[i] = mu[i] * mu[i];
    }

    // ---- k = 4..8 + epilogue ----
    {
      float tpB[5][4];
      {
        const int off[5] = {288, 320, 512, 544, 576};  // k=4..8
#pragma unroll
        for (int k = 0; k < 5; ++k) {
          const float4 t = *(const float4*)&padT[pb + off[k]];
          tpB[k][0] = t.x; tpB[k][1] = t.y; tpB[k][2] = t.z; tpB[k][3] = t.w;
        }
      }
#pragma unroll
      for (int j = 0; j < 6; ++j) {
        const float4 wb = *(const float4*)&buf[(rthr + 8 * j) * 12 + 4];
        const float4 wc = *(const float4*)&buf[(rthr + 8 * j) * 12 + 8];
#pragma unroll
        for (int i = 0; i < 4; ++i) {
          float ev = e[i][j];
          ev = fmaf(tpB[0][i], wb.x, ev);
          ev = fmaf(tpB[1][i], wb.y, ev);
          ev = fmaf(tpB[2][i], wb.z, ev);
          ev = fmaf(tpB[3][i], wb.w, ev);
          ev = fmaf(tpB[4][i], wc.x, ev);
          // wc.y = 2*mu_r, wc.z = mu_r^2+C1, wc.w = sig_r+C2
          const float am = mu[i] * wc.y;             // 2*mt*mr
          const float n1 = am + kC1;
          const float n2 = ev - am;                  // 2*sig_tr + C2
          const float d1 = mt2[i] + wc.z;            // mt^2+mr^2+C1
          const float d2 = sg[i] + wc.w;
          const float nn = n1 * n2;
          const float dd = d1 * d2;
          // rcp + 1 Newton step: ~1e-7 rel error, no IEEE div, 1 accum reg.
          const float r0v = __builtin_amdgcn_rcpf(dd);
          const float r1v = r0v * fmaf(-dd, r0v, 2.0f);
          score[i][j] = fmaf(nn, r1v, score[i][j]);
        }
      }
    }

    pb += (w6 == 5) ? 96 : 32;       // col step 32; row wrap: +3 window cols
    w6 = (w6 == 5) ? 0 : w6 + 1;
    sbase += 32;
  }

  // sb overlay: all waves must be done with padT/statT/refbuf
  __syncthreads();
  float* sb = smem;   // [8][32][49]
#pragma unroll
  for (int i = 0; i < 4; ++i)
#pragma unroll
    for (int j = 0; j < 6; ++j)
      sb[w * 1568 + (tl0 + i) * 49 + (rthr * 6 + j)] = score[i][j];
  __syncthreads();

  // Reduce 8 wave-partials + density penalty + per-tile argmax
  {
    const int tile = tid >> 4, rt = tid & 15;
    const float dt = densT[tile];
    float best = -1e30f; int bi = 0;
#pragma unroll
    for (int q = 0; q < 3; ++q) {
      const int rr = rt * 3 + q;
      const int rg = half * 48 + rr;
      if (rg < 95) {
        float s = 0.f;
#pragma unroll
        for (int g = 0; g < 8; ++g) s += sb[g * 1568 + tile * 49 + rr];
        s = s * (1.0f / 96.0f) - 3.0f * fabsf(dt - densR[rg]);
        if (s > best) { best = s; bi = rg; }   // ascending r, strict >
      }
    }
#pragma unroll
    for (int m = 8; m >= 1; m >>= 1) {
      const float ob = __shfl_xor(best, m, 64);
      const int oi = __shfl_xor(bi, m, 64);
      if (ob > best || (ob == best && oi < bi)) { best = ob; bi = oi; }
    }
    if (rt == 0)
      scratch[half * 8192 + row0 * 128 + c0 + tile] = make_float2(best, (float)bi);
  }
}

// ---------------- Kernel 3: combine ref-halves ----------------
__global__ __launch_bounds__(256) void combine_kernel(
    const float2* __restrict__ scratch, int* __restrict__ out) {
  const int t = blockIdx.x * 256 + threadIdx.x;   // 0..8191
  const float2 a = scratch[t];
  const float2 b = scratch[8192 + t];
  out[t] = (b.x > a.x) ? (int)b.y : (int)a.y;     // ties -> half0 (lower r)
}

// ---------------- Host launch ----------------
extern "C" void kernel_launch(void* const* d_in, const int* in_sizes, int n_in,
                              void* d_out, int out_size, void* d_ws, size_t ws_size,
                              hipStream_t stream) {
  (void)in_sizes; (void)n_in; (void)out_size; (void)ws_size;
  const float* img = (const float*)d_in[0];
  const float* chars = (const float*)d_in[1];
  int* out = (int*)d_out;
  float* refdata = (float*)d_ws;                  // 96*2*48*12 = 110592 floats
  float* densR = refdata + 110592;                // +96
  float2* scratch = (float2*)(refdata + 110688);  // 2*8192 float2

  KF kf;
  {
    float gg[3], s = 0.f;
    for (int i = 0; i < 3; ++i) {
      const float c = (float)i - 1.0f;
      gg[i] = expf(-(c * c) / (2.0f * 1.5f * 1.5f));
      s += gg[i];
    }
    float gn[3];
    for (int i = 0; i < 3; ++i) gn[i] = gg[i] / s;
    float k2[9]; float ks = 0.f;
    for (int i = 0; i < 3; ++i)
      for (int j = 0; j < 3; ++j) { k2[i * 3 + j] = gn[i] * gn[j]; ks += k2[i * 3 + j]; }
    for (int k = 0; k < 9; ++k) kf.k[k] = k2[k] / ks;
  }

  hipLaunchKernelGGL(refprep_kernel, dim3(96), dim3(128), 0, stream,
                     chars, refdata, densR, kf);
  hipLaunchKernelGGL(ssim_main_kernel, dim3(512), dim3(512), 0, stream,
                     img, refdata, densR, scratch, kf);
  hipLaunchKernelGGL(combine_kernel, dim3(32), dim3(256), 0, stream,
                     scratch, out);
}

// Round 7
// 50.382 us; speedup vs baseline: 1.2562x; 1.2555x over previous
//
#include <hip/hip_runtime.h>
#include <math.h>

// SSIM char-matcher: img (1,1,1024,768) f32, chars (95,1,16,6) f32 -> argmax idx [64][128] int32
// H=16, W=6, WIN=3, tiles T=8192 (64 rows x 128 cols), refs R=95 (pad to 96)
// Grid: 256 blocks = (64 rows) x (4 col-groups of 32 tiles); all 96 refs in-block.

static constexpr float kC1 = 1.0e-4f;   // 0.01^2
static constexpr float kC2 = 9.0e-4f;   // 0.03^2

struct KF { float k[9]; };

__device__ __forceinline__ int refl(int x, int n) {
  if (x < 0) return -x;
  if (x >= n) return 2 * n - 2 - x;
  return x;
}

// ---------------- Kernel 1: per-ref precompute ----------------
// refdata: per hw a chunk of 96 rows x 12 floats (4608 B, contiguous).
// Logical ref r (0..95) stored at physical row rp = r/6 + 16*(r%6)
// (bijective; main kernel's lane rthr reads ref rthr*6+j at row rthr+16j ->
// 16 consecutive rows per j, stride 48 B -> 2-way banks = free).
// Row: f0..8 = 2*k[k]*Rp[k] (DOUBLED), f9 = 2*mu_r (DOUBLED),
// f10 = mu_r^2 + C1, f11 = sig_r + C2.  r=95 is padding (never argmax'd).
__global__ __launch_bounds__(128) void refprep_kernel(
    const float* __restrict__ chars, float* __restrict__ refdata,
    float* __restrict__ densR, KF kf) {
  const int hw = blockIdx.x;   // 0..95
  const int r = threadIdx.x;   // 0..127
  if (r >= 96) return;
  const int rp = r / 6 + 16 * (r % 6);
  float* row = refdata + ((size_t)hw * 96 + rp) * 12;
  const int h = hw / 6, w = hw % 6;
  if (r < 95) {
    const float* cb = chars + r * 96;
    float mu = 0.f, ex2 = 0.f;
    float wrv[9];
#pragma unroll
    for (int i = 0; i < 3; ++i) {
      const int hh = refl(h + i - 1, 16);
#pragma unroll
      for (int j = 0; j < 3; ++j) {
        const int ww = refl(w + j - 1, 6);
        const float p = cb[hh * 6 + ww];
        const float kv = kf.k[i * 3 + j];
        wrv[i * 3 + j] = 2.0f * kv * p;
        mu += kv * p;
        ex2 += kv * p * p;
      }
    }
    const float sig = ex2 - mu * mu;
#pragma unroll
    for (int k = 0; k < 9; ++k) row[k] = wrv[k];
    row[9]  = 2.0f * mu;
    row[10] = mu * mu + kC1;
    row[11] = sig + kC2;
  } else {
#pragma unroll
    for (int k = 0; k < 9; ++k) row[k] = 0.f;
    row[9]  = 0.f;
    row[10] = kC1;
    row[11] = kC2;
  }
  if (hw == 0) {
    if (r < 95) {
      float s = 0.f;
      for (int i = 0; i < 96; ++i) s += chars[r * 96 + i];
      densR[r] = s * (1.0f / 96.0f);
    } else {
      densR[r] = 0.f;
    }
  }
}

// ---- async global->LDS staging of one 1152-float (4608 B) ref chunk ----
// 4 x (64 lanes x 16B) + 2 x (64 lanes x 4B); counts 6 on vmcnt.
__device__ __forceinline__ void stage_px(const float* __restrict__ src,
                                         float* dst, int lane) {
  const uintptr_t gs = (uintptr_t)src;
  const uintptr_t ls = (uintptr_t)dst;
#define G_(off) ((const __attribute__((address_space(1))) void*)(gs + (off)))
#define L_(off) ((__attribute__((address_space(3))) void*)(uint32_t)(ls + (off)))
  __builtin_amdgcn_global_load_lds(G_(0    + lane * 16), L_(0),    16, 0, 0);
  __builtin_amdgcn_global_load_lds(G_(1024 + lane * 16), L_(1024), 16, 0, 0);
  __builtin_amdgcn_global_load_lds(G_(2048 + lane * 16), L_(2048), 16, 0, 0);
  __builtin_amdgcn_global_load_lds(G_(3072 + lane * 16), L_(3072), 16, 0, 0);
  __builtin_amdgcn_global_load_lds(G_(4096 + lane * 4),  L_(4096), 4, 0, 0);
  __builtin_amdgcn_global_load_lds(G_(4352 + lane * 4),  L_(4352), 4, 0, 0);
#undef G_
#undef L_
}

// ---------------- Kernel 2: main SSIM + argmax ----------------
// 256 blocks x 512 threads (8 waves). Block = 32 tiles x 96 refs x 96 px.
// Wave w owns px [12w, 12w+12) = 2 full pixel-rows.
// lane = tthr(4 x 8 tiles) x rthr(16 x 6 refs) -> 48 el/thread.
// Rationale (R3-R6 post-mortem): the limiter was LDS operand bytes/element
// (19 B/el at 4x6) + latency chains, not occupancy/spills. 8x6 halves LDS
// bytes/el (~10 B/el): ~19us/CU LDS vs ~20us VALU floor -> balanced pipes.
// Wave-private double-buffered ref chunk, zero main-loop barriers, counted
// vmcnt(6). Score via rcp + 1 Newton step.
// __launch_bounds__(512,2): the only spelling on this toolchain that grants
// a 256-VGPR budget (R2 evidence); pressure ~180 -> no spills, 2 waves/SIMD,
// 1 block/CU (LDS 117 KB).
__global__ __launch_bounds__(512, 2)
void ssim_main_kernel(
    const float* __restrict__ img, const float* __restrict__ refdata,
    const float* __restrict__ densR, int* __restrict__ out, KF kf) {
  // [0:4608) padT [144][32] | [4608:10752) statT [2][96][32] |
  // [10752:29184) refbuf 8 waves x 2 x 1152.  Overlay after loop: sb[8][32][97].
  __shared__ float smem[29184];
  __shared__ float densT[32];
  float* padT = smem;
  float* statT = smem + 4608;

  const int tid = threadIdx.x;
  const int w = tid >> 6;
  const int lane = tid & 63;
  const int tthr = lane >> 4;      // 0..3  -> 8 tiles each
  const int rthr = lane & 15;      // 0..15 -> 6 refs each
  const int tl0 = tthr * 8;
  const int blk = blockIdx.x;
  const int row0 = blk >> 2;           // tile-row 0..63
  const int c0 = (blk & 3) * 32;       // tile-col base
  const int hwBase = w * 12;           // wave = 2 full px-rows
  float* rbuf = smem + 10752 + w * 2304;   // wave-private 2 x 1152

  // Issue px0 staging immediately; the first __syncthreads drains it.
  stage_px(refdata + (size_t)hwBase * 1152, rbuf, lane);

  // Phase A: reflect-padded tiles, transposed: padT[c(0..143)][tile(0..31)]
  for (int idx = tid; idx < 4608; idx += 512) {
    const int c = idx >> 5, tl = idx & 31;
    const int ph = c >> 3, pw = c & 7;
    const int h = refl(ph - 1, 16), ww = refl(pw - 1, 6);
    padT[idx] = img[(row0 * 16 + h) * 768 + (c0 + tl) * 6 + ww];
  }
  __syncthreads();

  if (tid < 32) {
    float s = 0.f;
    for (int h = 0; h < 16; ++h)
      for (int ww = 0; ww < 6; ++ww)
        s += padT[((h + 1) * 8 + (ww + 1)) * 32 + tid];
    densT[tid] = s * (1.0f / 96.0f);
  }
  // Phase B: per-(hw, tile) stats: mu, sig
  for (int idx = tid; idx < 3072; idx += 512) {
    const int hw = idx >> 5, tl = idx & 31;
    const int h = hw / 6, ww = hw % 6;
    float mu = 0.f, ex2 = 0.f;
#pragma unroll
    for (int i = 0; i < 3; ++i)
#pragma unroll
      for (int j = 0; j < 3; ++j) {
        const float p = padT[((h + i) * 8 + (ww + j)) * 32 + tl];
        const float kv = kf.k[i * 3 + j];
        mu += kv * p;
        ex2 += kv * p * p;
      }
    statT[idx] = mu;
    statT[3072 + idx] = ex2 - mu * mu;
  }
  __syncthreads();

  float score[8][6];
#pragma unroll
  for (int i = 0; i < 8; ++i)
#pragma unroll
    for (int j = 0; j < 6; ++j) score[i][j] = 0.f;

  // Incremental addressing: w6 cycles 0..5 twice (2 pixel-rows).
  int pb = (2 * w) * 8 * 32 + tl0;     // padT offset of window origin
  int sbase = hwBase * 32 + tl0;       // statT offset
  const float* refsrc = refdata + (size_t)(hwBase + 1) * 1152;
  int w6 = 0;

#pragma unroll 1
  for (int it = 0; it < 12; ++it) {
    const float* buf = rbuf + (it & 1) * 1152;

    if (it < 11) {
      // Restaged buffer's last ds_reads were consumed in it-1 (data already
      // in VGPRs) -> WAR-safe without lgkm fence. Counted vmcnt: this px's
      // 6 loads complete, next px's 6 stay in flight.
      stage_px(refsrc, rbuf + ((it + 1) & 1) * 1152, lane);
      asm volatile("s_waitcnt vmcnt(6)" ::: "memory");
    } else {
      asm volatile("s_waitcnt vmcnt(0)" ::: "memory");
    }
    refsrc += 1152;

    // Tile window pixels: 9 taps x 8 tiles (18 x ds_read_b128)
    float tp[9][8];
#pragma unroll
    for (int ik = 0; ik < 3; ++ik)
#pragma unroll
      for (int jk = 0; jk < 3; ++jk) {
        const int k = ik * 3 + jk;
        const float4 a = *(const float4*)&padT[pb + (ik * 8 + jk) * 32];
        const float4 b = *(const float4*)&padT[pb + (ik * 8 + jk) * 32 + 4];
        tp[k][0] = a.x; tp[k][1] = a.y; tp[k][2] = a.z; tp[k][3] = a.w;
        tp[k][4] = b.x; tp[k][5] = b.y; tp[k][6] = b.z; tp[k][7] = b.w;
      }

    // tile stats (8 tiles): mu, sig
    float mu[8], sg[8], mt2[8];
    {
      float4 v;
      v = *(const float4*)&statT[sbase];            mu[0]=v.x; mu[1]=v.y; mu[2]=v.z; mu[3]=v.w;
      v = *(const float4*)&statT[sbase + 4];        mu[4]=v.x; mu[5]=v.y; mu[6]=v.z; mu[7]=v.w;
      v = *(const float4*)&statT[3072 + sbase];     sg[0]=v.x; sg[1]=v.y; sg[2]=v.z; sg[3]=v.w;
      v = *(const float4*)&statT[3072 + sbase + 4]; sg[4]=v.x; sg[5]=v.y; sg[6]=v.z; sg[7]=v.w;
#pragma unroll
      for (int i = 0; i < 8; ++i) mt2[i] = mu[i] * mu[i];
    }

#pragma unroll
    for (int j = 0; j < 6; ++j) {
      const int rb = (rthr + 16 * j) * 12;
      const float4 wa = *(const float4*)&buf[rb];
      const float4 wb = *(const float4*)&buf[rb + 4];
      const float4 wc = *(const float4*)&buf[rb + 8];
#pragma unroll
      for (int i = 0; i < 8; ++i) {
        float ev = fmaf(tp[0][i], wa.x, kC2);
        ev = fmaf(tp[1][i], wa.y, ev);
        ev = fmaf(tp[2][i], wa.z, ev);
        ev = fmaf(tp[3][i], wa.w, ev);
        ev = fmaf(tp[4][i], wb.x, ev);
        ev = fmaf(tp[5][i], wb.y, ev);
        ev = fmaf(tp[6][i], wb.z, ev);
        ev = fmaf(tp[7][i], wb.w, ev);
        ev = fmaf(tp[8][i], wc.x, ev);
        // wc.y = 2*mu_r, wc.z = mu_r^2+C1, wc.w = sig_r+C2
        const float am = mu[i] * wc.y;             // 2*mt*mr
        const float n1 = am + kC1;
        const float n2 = ev - am;                  // 2*sig_tr + C2
        const float d1 = mt2[i] + wc.z;            // mt^2+mr^2+C1
        const float d2 = sg[i] + wc.w;
        const float nn = n1 * n2;
        const float dd = d1 * d2;
        // rcp + 1 Newton step: ~1e-7 rel error, no IEEE div.
        const float r0v = __builtin_amdgcn_rcpf(dd);
        const float r1v = r0v * fmaf(-dd, r0v, 2.0f);
        score[i][j] = fmaf(nn, r1v, score[i][j]);
      }
    }

    pb += (w6 == 5) ? 96 : 32;       // col step 32; row wrap: +3 window cols
    w6 = (w6 == 5) ? 0 : w6 + 1;
    sbase += 32;
  }

  // sb overlay: all waves done with padT/statT/refbuf
  __syncthreads();
  float* sb = smem;   // [8][32][97]
#pragma unroll
  for (int i = 0; i < 8; ++i)
#pragma unroll
    for (int j = 0; j < 6; ++j)
      sb[w * 3104 + (tl0 + i) * 97 + (rthr * 6 + j)] = score[i][j];
  __syncthreads();

  // Reduce 8 wave-partials + density penalty + per-tile argmax (all 95 refs)
  {
    const int tile = tid >> 4, rt = tid & 15;
    const float dt = densT[tile];
    float best = -1e30f; int bi = 0;
#pragma unroll
    for (int q = 0; q < 6; ++q) {
      const int r = rt * 6 + q;
      if (r < 95) {
        float s = 0.f;
#pragma unroll
        for (int g = 0; g < 8; ++g) s += sb[g * 3104 + tile * 97 + r];
        s = s * (1.0f / 96.0f) - 3.0f * fabsf(dt - densR[r]);
        if (s > best) { best = s; bi = r; }   // ascending r, strict >
      }
    }
#pragma unroll
    for (int m = 8; m >= 1; m >>= 1) {
      const float ob = __shfl_xor(best, m, 64);
      const int oi = __shfl_xor(bi, m, 64);
      if (ob > best || (ob == best && oi < bi)) { best = ob; bi = oi; }
    }
    if (rt == 0) out[row0 * 128 + c0 + tile] = bi;
  }
}

// ---------------- Host launch ----------------
extern "C" void kernel_launch(void* const* d_in, const int* in_sizes, int n_in,
                              void* d_out, int out_size, void* d_ws, size_t ws_size,
                              hipStream_t stream) {
  (void)in_sizes; (void)n_in; (void)out_size; (void)ws_size;
  const float* img = (const float*)d_in[0];
  const float* chars = (const float*)d_in[1];
  int* out = (int*)d_out;
  float* refdata = (float*)d_ws;                  // 96*96*12 = 110592 floats
  float* densR = refdata + 110592;                // +96

  KF kf;
  {
    float gg[3], s = 0.f;
    for (int i = 0; i < 3; ++i) {
      const float c = (float)i - 1.0f;
      gg[i] = expf(-(c * c) / (2.0f * 1.5f * 1.5f));
      s += gg[i];
    }
    float gn[3];
    for (int i = 0; i < 3; ++i) gn[i] = gg[i] / s;
    float k2[9]; float ks = 0.f;
    for (int i = 0; i < 3; ++i)
      for (int j = 0; j < 3; ++j) { k2[i * 3 + j] = gn[i] * gn[j]; ks += k2[i * 3 + j]; }
    for (int k = 0; k < 9; ++k) kf.k[k] = k2[k] / ks;
  }

  hipLaunchKernelGGL(refprep_kernel, dim3(96), dim3(128), 0, stream,
                     chars, refdata, densR, kf);
  hipLaunchKernelGGL(ssim_main_kernel, dim3(256), dim3(512), 0, stream,
                     img, refdata, densR, out, kf);
}